// Round 8
// baseline (247.627 us; speedup 1.0000x reference)
//
#include <hip/hip_runtime.h>

// VectorQuantizer: N=131072 tokens, D=64, K=1024 codes.
// out (f32 concat): [0,8388608) quant, [8388608] loss, [8388609,...) idx.
//
// R8: R7's dist (92.5us) had MfmaUtil 22% with MFMA-busy ~= the 25us floor:
// per-tile 6-MFMA dependency chains + epilogue stalls, 8x-redundant A-frag
// build across K-splits, and 33MB of atomicMin line writebacks. Fix: one
// block = 256 tokens x ALL 1024 codes (grid 512 = 2 blocks/CU); B-frags
// stream via 2x32KB LDS double-buffer (register-staged, loads first /
// writes last per q); MFMA issued STEP-MAJOR across ms -> 4 independent
// acc chains (per-acc order unchanged -> identical rounding); argmin fully
// in registers over ascending q (first-min preserved); final key = plain
// u64 store (single writer, no atomics, no packed-init).
// Distance math unchanged since R4: fp16 split-product MFMA
// (hi*hi + hi*lo + lo*hi), np8 x2/e2, s = fma(-2,dot,x2+e2).

#define KC 1024
#define DD 64
#define NTOK (32 * 4096)
#define QUANT_ELEMS ((size_t)NTOK * DD)        // 8388608
#define LOSS_OFF QUANT_ELEMS
#define IDX_OFF (QUANT_ELEMS + 1)

// ws float-word offsets
#define WS_E2 0                      // 1024 f32
#define WS_X2 2048                   // NTOK f32
#define WS_PACKED_F (2048 + NTOK)    // NTOK u64 (plain, written once)
#define WS_BFRAG_F (WS_PACKED_F + 2 * NTOK)  // 16384 f16x8 = 65536 f32 words
#define WS_BSUM (WS_BFRAG_F + 65536) // 2048 f32 per-block loss partials

#define COMBINE_BLOCKS (NTOK / 64)   // 2048

typedef _Float16 f16x8 __attribute__((ext_vector_type(8)));
typedef float f32x4 __attribute__((ext_vector_type(4)));

__device__ __forceinline__ unsigned int sortable_bits(float f) {
  unsigned int b = __float_as_uint(f);
  return b ^ (unsigned int)(((int)b >> 31) | 0x80000000);
}

// np pairwise-8 sum of squares of a 64-float row
__device__ __forceinline__ float row_sumsq_np8(const float* p) {
  float r[8];
#pragma unroll
  for (int j = 0; j < 8; ++j) r[j] = p[j] * p[j];
#pragma unroll
  for (int i = 1; i < 8; ++i)
#pragma unroll
    for (int j = 0; j < 8; ++j) {
      float v = p[i * 8 + j];
      r[j] += v * v;
    }
  return ((r[0] + r[1]) + (r[2] + r[3])) + ((r[4] + r[5]) + (r[6] + r[7]));
}

// blocks [0,512): x2; [512,576): B-frag build; [576,580): e2
__global__ void vq_setup(const float* __restrict__ x_in,
                         const float* __restrict__ emb,
                         float* __restrict__ ws) {
  const int b = blockIdx.x;
  const int tid = threadIdx.x;
  if (b < 512) {
    const int t = b * 256 + tid;
    ws[WS_X2 + t] = row_sumsq_np8(x_in + (size_t)t * DD);
  } else if (b < 576) {
    const int nt = b - 512;            // global tile 0..63 (16 codes each)
    const int f = tid >> 6;            // 0..3: plane(hi/lo) x kstep
    const int lane = tid & 63;
    const int plane = f >> 1, ks = f & 1;
    const int n = nt * 16 + (lane & 15);
    const int kb = ks * 32 + ((lane >> 4) & 3) * 8;
    const float* ep = emb + (size_t)n * DD + kb;
    f16x8 o;
#pragma unroll
    for (int j = 0; j < 8; ++j) {
      float v = ep[j];
      _Float16 h = (_Float16)v;
      o[j] = (plane == 0) ? h : (_Float16)(v - (float)h);
    }
    ((f16x8*)(ws + WS_BFRAG_F))[(nt * 4 + f) * 64 + lane] = o;
  } else {
    const int k = (b - 576) * 256 + tid;  // 0..1023
    ws[WS_E2 + k] = row_sumsq_np8(emb + (size_t)k * DD);
  }
}

__launch_bounds__(256, 2)
__global__ void vq_dist_mfma(const float* __restrict__ x_in,
                             const float* __restrict__ ws_ro,
                             unsigned long long* __restrict__ packed) {
  const int tid = threadIdx.x;
  const int wave = tid >> 6, lane = tid & 63;
  const int quad = lane >> 4, l16 = lane & 15;
  const int tokBase = blockIdx.x * 256 + wave * 64;

  __shared__ float4 Bf[2][2048];   // 2 x 32 KB double buffer
  __shared__ float E2s[KC];        // 4 KB

  const float4* bsrc = (const float4*)(ws_ro + WS_BFRAG_F);

  // Preload q=0 B-frags into registers; stage e2 table to LDS.
  float4 st[8];
#pragma unroll
  for (int i = 0; i < 8; ++i) st[i] = bsrc[i * 256 + tid];
#pragma unroll
  for (int i = 0; i < 4; ++i)
    E2s[i * 256 + tid] = ws_ro[WS_E2 + i * 256 + tid];

  // A fragments: 4 m-sets of 16 tokens; split x into fp16 hi/lo planes.
  f16x8 ah[4][2], al[4][2];
#pragma unroll
  for (int ms = 0; ms < 4; ++ms) {
    const float* xr = x_in + (size_t)(tokBase + ms * 16 + l16) * DD;
#pragma unroll
    for (int ks = 0; ks < 2; ++ks) {
      const float4* p = (const float4*)(xr + ks * 32 + quad * 8);
      float4 v0 = p[0], v1 = p[1];
      float vv[8] = {v0.x, v0.y, v0.z, v0.w, v1.x, v1.y, v1.z, v1.w};
#pragma unroll
      for (int j = 0; j < 8; ++j) {
        _Float16 h = (_Float16)vv[j];
        ah[ms][ks][j] = h;
        al[ms][ks][j] = (_Float16)(vv[j] - (float)h);
      }
    }
  }

  // x2 for this lane's C rows: token = tokBase + ms*16 + quad*4 + r
  float x2v[4][4];
#pragma unroll
  for (int ms = 0; ms < 4; ++ms)
#pragma unroll
    for (int r = 0; r < 4; ++r)
      x2v[ms][r] = ws_ro[WS_X2 + tokBase + ms * 16 + quad * 4 + r];

#pragma unroll
  for (int i = 0; i < 8; ++i) Bf[0][i * 256 + tid] = st[i];

  float best[4][4];
  int bidx[4][4];
#pragma unroll
  for (int ms = 0; ms < 4; ++ms)
#pragma unroll
    for (int r = 0; r < 4; ++r) { best[ms][r] = 3.402823466e38f; bidx[ms][r] = 0; }

  __syncthreads();  // buf0 + E2s ready

  for (int q = 0; q < 8; ++q) {
    const int buf = q & 1;
    // issue next stage's global loads first (latency overlapped by tiles)
    if (q < 7) {
#pragma unroll
      for (int i = 0; i < 8; ++i)
        st[i] = bsrc[(q + 1) * 2048 + i * 256 + tid];
    }
    const f16x8* bfp = (const f16x8*)Bf[buf];
#pragma unroll
    for (int nt = 0; nt < 8; ++nt) {
      const int ch = nt * 4;
      f16x8 bh0 = bfp[(ch + 0) * 64 + lane];
      f16x8 bh1 = bfp[(ch + 1) * 64 + lane];
      f16x8 bl0 = bfp[(ch + 2) * 64 + lane];
      f16x8 bl1 = bfp[(ch + 3) * 64 + lane];
      const int ncur = q * 128 + nt * 16 + l16;   // this lane's code column
      const float e2v = E2s[ncur];
      f32x4 acc[4];
#pragma unroll
      for (int ms = 0; ms < 4; ++ms) acc[ms] = (f32x4){0.f, 0.f, 0.f, 0.f};
      // step-major: 4 independent chains; per-acc order identical to R4-R7
#pragma unroll
      for (int ms = 0; ms < 4; ++ms)
        acc[ms] = __builtin_amdgcn_mfma_f32_16x16x32_f16(ah[ms][0], bh0, acc[ms], 0, 0, 0);
#pragma unroll
      for (int ms = 0; ms < 4; ++ms)
        acc[ms] = __builtin_amdgcn_mfma_f32_16x16x32_f16(ah[ms][1], bh1, acc[ms], 0, 0, 0);
#pragma unroll
      for (int ms = 0; ms < 4; ++ms)
        acc[ms] = __builtin_amdgcn_mfma_f32_16x16x32_f16(al[ms][0], bh0, acc[ms], 0, 0, 0);
#pragma unroll
      for (int ms = 0; ms < 4; ++ms)
        acc[ms] = __builtin_amdgcn_mfma_f32_16x16x32_f16(al[ms][1], bh1, acc[ms], 0, 0, 0);
#pragma unroll
      for (int ms = 0; ms < 4; ++ms)
        acc[ms] = __builtin_amdgcn_mfma_f32_16x16x32_f16(ah[ms][0], bl0, acc[ms], 0, 0, 0);
#pragma unroll
      for (int ms = 0; ms < 4; ++ms)
        acc[ms] = __builtin_amdgcn_mfma_f32_16x16x32_f16(ah[ms][1], bl1, acc[ms], 0, 0, 0);
#pragma unroll
      for (int ms = 0; ms < 4; ++ms)
#pragma unroll
        for (int r = 0; r < 4; ++r) {
          float s = __builtin_fmaf(-2.0f, acc[ms][r], x2v[ms][r] + e2v);
          if (s < best[ms][r]) { best[ms][r] = s; bidx[ms][r] = ncur; }
        }
    }
    if (q < 7) {
#pragma unroll
      for (int i = 0; i < 8; ++i) Bf[buf ^ 1][i * 256 + tid] = st[i];
    }
    __syncthreads();
  }

  // Reduce across the 16 lanes of each quad; single writer -> plain store.
#pragma unroll
  for (int ms = 0; ms < 4; ++ms)
#pragma unroll
    for (int r = 0; r < 4; ++r) {
      unsigned long long key =
          ((unsigned long long)sortable_bits(best[ms][r]) << 32) |
          (unsigned int)bidx[ms][r];
#pragma unroll
      for (int m = 1; m < 16; m <<= 1) {
        unsigned long long o = __shfl_xor(key, m);
        key = o < key ? o : key;
      }
      if (l16 == 0)
        packed[tokBase + ms * 16 + quad * 4 + r] = key;
    }
}

// 4 lanes per token: gather winning e-row, write quant+idx, loss from key.
__global__ void vq_combine(const float* __restrict__ emb,
                           const unsigned long long* __restrict__ packed,
                           float* __restrict__ out,
                           float* __restrict__ blocksum) {
  const int tid = threadIdx.x;
  const int token = blockIdx.x * 64 + (tid >> 2);
  const int part = tid & 3;

  const unsigned long long key = packed[token];
  const int bidx = (int)(unsigned int)key;

  float err = 0.0f;
  if (part == 0) {
    out[IDX_OFF + (size_t)token] = (float)bidx;
    unsigned int u = (unsigned int)(key >> 32);
    unsigned int fb = (u & 0x80000000u) ? (u ^ 0x80000000u) : ~u;
    err = __uint_as_float(fb);  // min distance == |x - e|^2 (expanded form)
  }

  const float4* eq = (const float4*)(emb + (size_t)bidx * DD) + part * 4;
  float4* op = (float4*)(out + (size_t)token * DD) + part * 4;
  float4 v0 = eq[0], v1 = eq[1], v2 = eq[2], v3 = eq[3];
  op[0] = v0; op[1] = v1; op[2] = v2; op[3] = v3;

#pragma unroll
  for (int off = 32; off > 0; off >>= 1) err += __shfl_down(err, off);
  __shared__ float wsum[4];
  const int wid = tid >> 6;
  if ((tid & 63) == 0) wsum[wid] = err;
  __syncthreads();
  if (tid == 0)
    blocksum[blockIdx.x] = (wsum[0] + wsum[1]) + (wsum[2] + wsum[3]);
}

// 1 block: reduce 2048 per-block partials -> loss
__global__ void vq_finish(const float* __restrict__ blocksum,
                          float* __restrict__ out) {
  const int tid = threadIdx.x;
  float s = 0.0f;
#pragma unroll
  for (int i = 0; i < COMBINE_BLOCKS / 256; ++i)
    s += blocksum[i * 256 + tid];
#pragma unroll
  for (int off = 32; off > 0; off >>= 1) s += __shfl_down(s, off);
  __shared__ float wsum[4];
  const int wid = tid >> 6;
  if ((tid & 63) == 0) wsum[wid] = s;
  __syncthreads();
  if (tid == 0) {
    float total = (wsum[0] + wsum[1]) + (wsum[2] + wsum[3]);
    float m = total / (float)QUANT_ELEMS;
    out[LOSS_OFF] = m + 0.25f * m;  // q_latent + COMMITMENT_COST * e_latent
  }
}

extern "C" void kernel_launch(void* const* d_in, const int* in_sizes, int n_in,
                              void* d_out, int out_size, void* d_ws, size_t ws_size,
                              hipStream_t stream) {
  const float* x = (const float*)d_in[0];
  const float* emb = (const float*)d_in[1];
  float* out = (float*)d_out;
  float* ws = (float*)d_ws;
  unsigned long long* packed = (unsigned long long*)(ws + WS_PACKED_F);

  vq_setup<<<580, 256, 0, stream>>>(x, emb, ws);
  vq_dist_mfma<<<NTOK / 256, 256, 0, stream>>>(x, ws, packed);
  vq_combine<<<COMBINE_BLOCKS, 256, 0, stream>>>(emb, packed, out, ws + WS_BSUM);
  vq_finish<<<1, 256, 0, stream>>>(ws + WS_BSUM, out);
}

// Round 9
// 153.507 us; speedup vs baseline: 1.6131x; 1.6131x over previous
//
#include <hip/hip_runtime.h>

// VectorQuantizer: N=131072 tokens, D=64, K=1024 codes.
// out (f32 concat): [0,8388608) quant, [8388608] loss, [8388609,...) idx.
//
// R9: R8 spilled (needed ~160 VGPR, allocator capped 128 -> 500MB scratch).
// Same full-K-per-block structure with HALVED register footprint:
// 2 m-sets (128 tokens/block, grid 1024 = 4 blocks/CU), 16 stages x 16KB
// double-buffered B-frags (2x16KB + 4KB e2 = 36KB LDS -> 4 blocks/CU),
// st[4] register staging, acc[2] step-major chains. ~110 VGPR < 128 cap.
// Empirical: launch_bounds(256,2) -> 128-VGPR ceiling (R4:88, R7:116 ok;
// R8:160 spilled). Argmin in registers over ascending q/nt (first-min
// preserved); plain u64 store (no atomics). Distance math unchanged since
// R4: fp16 split-product MFMA (hi*hi+hi*lo+lo*hi), np8 x2/e2,
// s = fma(-2,dot,x2+e2). Combine/finish = R7 (no contended atomics).

#define KC 1024
#define DD 64
#define NTOK (32 * 4096)
#define QUANT_ELEMS ((size_t)NTOK * DD)        // 8388608
#define LOSS_OFF QUANT_ELEMS
#define IDX_OFF (QUANT_ELEMS + 1)

// ws float-word offsets
#define WS_E2 0                      // 1024 f32
#define WS_X2 2048                   // NTOK f32
#define WS_PACKED_F (2048 + NTOK)    // NTOK u64 (plain, written once)
#define WS_BFRAG_F (WS_PACKED_F + 2 * NTOK)  // 16384 f16x8 = 65536 f32 words
#define WS_BSUM (WS_BFRAG_F + 65536) // 2048 f32 per-block loss partials

#define COMBINE_BLOCKS (NTOK / 64)   // 2048

typedef _Float16 f16x8 __attribute__((ext_vector_type(8)));
typedef float f32x4 __attribute__((ext_vector_type(4)));

__device__ __forceinline__ unsigned int sortable_bits(float f) {
  unsigned int b = __float_as_uint(f);
  return b ^ (unsigned int)(((int)b >> 31) | 0x80000000);
}

// np pairwise-8 sum of squares of a 64-float row
__device__ __forceinline__ float row_sumsq_np8(const float* p) {
  float r[8];
#pragma unroll
  for (int j = 0; j < 8; ++j) r[j] = p[j] * p[j];
#pragma unroll
  for (int i = 1; i < 8; ++i)
#pragma unroll
    for (int j = 0; j < 8; ++j) {
      float v = p[i * 8 + j];
      r[j] += v * v;
    }
  return ((r[0] + r[1]) + (r[2] + r[3])) + ((r[4] + r[5]) + (r[6] + r[7]));
}

// blocks [0,512): x2; [512,576): B-frag build; [576,580): e2
__global__ void vq_setup(const float* __restrict__ x_in,
                         const float* __restrict__ emb,
                         float* __restrict__ ws) {
  const int b = blockIdx.x;
  const int tid = threadIdx.x;
  if (b < 512) {
    const int t = b * 256 + tid;
    ws[WS_X2 + t] = row_sumsq_np8(x_in + (size_t)t * DD);
  } else if (b < 576) {
    const int nt = b - 512;            // global tile 0..63 (16 codes each)
    const int f = tid >> 6;            // 0..3: plane(hi/lo) x kstep
    const int lane = tid & 63;
    const int plane = f >> 1, ks = f & 1;
    const int n = nt * 16 + (lane & 15);
    const int kb = ks * 32 + ((lane >> 4) & 3) * 8;
    const float* ep = emb + (size_t)n * DD + kb;
    f16x8 o;
#pragma unroll
    for (int j = 0; j < 8; ++j) {
      float v = ep[j];
      _Float16 h = (_Float16)v;
      o[j] = (plane == 0) ? h : (_Float16)(v - (float)h);
    }
    ((f16x8*)(ws + WS_BFRAG_F))[(nt * 4 + f) * 64 + lane] = o;
  } else {
    const int k = (b - 576) * 256 + tid;  // 0..1023
    ws[WS_E2 + k] = row_sumsq_np8(emb + (size_t)k * DD);
  }
}

__launch_bounds__(256, 2)
__global__ void vq_dist_mfma(const float* __restrict__ x_in,
                             const float* __restrict__ ws_ro,
                             unsigned long long* __restrict__ packed) {
  const int tid = threadIdx.x;
  const int wave = tid >> 6, lane = tid & 63;
  const int quad = lane >> 4, l16 = lane & 15;
  const int tokBase = blockIdx.x * 128 + wave * 32;  // 32 tokens per wave

  __shared__ float4 Bf[2][1024];   // 2 x 16 KB double buffer
  __shared__ float E2s[KC];        // 4 KB

  const float4* bsrc = (const float4*)(ws_ro + WS_BFRAG_F);

  // Preload stage 0 B-frags into registers; stage e2 table to LDS.
  float4 st[4];
#pragma unroll
  for (int i = 0; i < 4; ++i) st[i] = bsrc[i * 256 + tid];
#pragma unroll
  for (int i = 0; i < 4; ++i)
    E2s[i * 256 + tid] = ws_ro[WS_E2 + i * 256 + tid];

  // A fragments: 2 m-sets of 16 tokens; split x into fp16 hi/lo planes.
  f16x8 ah[2][2], al[2][2];
#pragma unroll
  for (int ms = 0; ms < 2; ++ms) {
    const float* xr = x_in + (size_t)(tokBase + ms * 16 + l16) * DD;
#pragma unroll
    for (int ks = 0; ks < 2; ++ks) {
      const float4* p = (const float4*)(xr + ks * 32 + quad * 8);
      float4 v0 = p[0], v1 = p[1];
      float vv[8] = {v0.x, v0.y, v0.z, v0.w, v1.x, v1.y, v1.z, v1.w};
#pragma unroll
      for (int j = 0; j < 8; ++j) {
        _Float16 h = (_Float16)vv[j];
        ah[ms][ks][j] = h;
        al[ms][ks][j] = (_Float16)(vv[j] - (float)h);
      }
    }
  }

  // x2 for this lane's C rows: token = tokBase + ms*16 + quad*4 + r
  float x2v[2][4];
#pragma unroll
  for (int ms = 0; ms < 2; ++ms)
#pragma unroll
    for (int r = 0; r < 4; ++r)
      x2v[ms][r] = ws_ro[WS_X2 + tokBase + ms * 16 + quad * 4 + r];

#pragma unroll
  for (int i = 0; i < 4; ++i) Bf[0][i * 256 + tid] = st[i];

  float best[2][4];
  int bidx[2][4];
#pragma unroll
  for (int ms = 0; ms < 2; ++ms)
#pragma unroll
    for (int r = 0; r < 4; ++r) { best[ms][r] = 3.402823466e38f; bidx[ms][r] = 0; }

  __syncthreads();  // buf0 + E2s ready

  for (int q = 0; q < 16; ++q) {
    const int buf = q & 1;
    // issue next stage's global loads first (overlap with this stage's MFMA)
    if (q < 15) {
#pragma unroll
      for (int i = 0; i < 4; ++i)
        st[i] = bsrc[(q + 1) * 1024 + i * 256 + tid];
    }
    const f16x8* bfp = (const f16x8*)Bf[buf];
#pragma unroll
    for (int lt = 0; lt < 4; ++lt) {
      const int ch = lt * 4;
      f16x8 bh0 = bfp[(ch + 0) * 64 + lane];
      f16x8 bh1 = bfp[(ch + 1) * 64 + lane];
      f16x8 bl0 = bfp[(ch + 2) * 64 + lane];
      f16x8 bl1 = bfp[(ch + 3) * 64 + lane];
      const int ncur = q * 64 + lt * 16 + l16;    // this lane's code column
      const float e2v = E2s[ncur];
      f32x4 acc[2];
#pragma unroll
      for (int ms = 0; ms < 2; ++ms) acc[ms] = (f32x4){0.f, 0.f, 0.f, 0.f};
      // step-major: 2 independent chains; per-acc order identical to R4-R8
#pragma unroll
      for (int ms = 0; ms < 2; ++ms)
        acc[ms] = __builtin_amdgcn_mfma_f32_16x16x32_f16(ah[ms][0], bh0, acc[ms], 0, 0, 0);
#pragma unroll
      for (int ms = 0; ms < 2; ++ms)
        acc[ms] = __builtin_amdgcn_mfma_f32_16x16x32_f16(ah[ms][1], bh1, acc[ms], 0, 0, 0);
#pragma unroll
      for (int ms = 0; ms < 2; ++ms)
        acc[ms] = __builtin_amdgcn_mfma_f32_16x16x32_f16(al[ms][0], bh0, acc[ms], 0, 0, 0);
#pragma unroll
      for (int ms = 0; ms < 2; ++ms)
        acc[ms] = __builtin_amdgcn_mfma_f32_16x16x32_f16(al[ms][1], bh1, acc[ms], 0, 0, 0);
#pragma unroll
      for (int ms = 0; ms < 2; ++ms)
        acc[ms] = __builtin_amdgcn_mfma_f32_16x16x32_f16(ah[ms][0], bl0, acc[ms], 0, 0, 0);
#pragma unroll
      for (int ms = 0; ms < 2; ++ms)
        acc[ms] = __builtin_amdgcn_mfma_f32_16x16x32_f16(ah[ms][1], bl1, acc[ms], 0, 0, 0);
#pragma unroll
      for (int ms = 0; ms < 2; ++ms)
#pragma unroll
        for (int r = 0; r < 4; ++r) {
          float s = __builtin_fmaf(-2.0f, acc[ms][r], x2v[ms][r] + e2v);
          if (s < best[ms][r]) { best[ms][r] = s; bidx[ms][r] = ncur; }
        }
    }
    if (q < 15) {
#pragma unroll
      for (int i = 0; i < 4; ++i) Bf[buf ^ 1][i * 256 + tid] = st[i];
    }
    __syncthreads();
  }

  // Reduce across the 16 lanes of each quad; single writer -> plain store.
#pragma unroll
  for (int ms = 0; ms < 2; ++ms)
#pragma unroll
    for (int r = 0; r < 4; ++r) {
      unsigned long long key =
          ((unsigned long long)sortable_bits(best[ms][r]) << 32) |
          (unsigned int)bidx[ms][r];
#pragma unroll
      for (int m = 1; m < 16; m <<= 1) {
        unsigned long long o = __shfl_xor(key, m);
        key = o < key ? o : key;
      }
      if (l16 == 0)
        packed[tokBase + ms * 16 + quad * 4 + r] = key;
    }
}

// 4 lanes per token: gather winning e-row, write quant+idx, loss from key.
__global__ void vq_combine(const float* __restrict__ emb,
                           const unsigned long long* __restrict__ packed,
                           float* __restrict__ out,
                           float* __restrict__ blocksum) {
  const int tid = threadIdx.x;
  const int token = blockIdx.x * 64 + (tid >> 2);
  const int part = tid & 3;

  const unsigned long long key = packed[token];
  const int bidx = (int)(unsigned int)key;

  float err = 0.0f;
  if (part == 0) {
    out[IDX_OFF + (size_t)token] = (float)bidx;
    unsigned int u = (unsigned int)(key >> 32);
    unsigned int fb = (u & 0x80000000u) ? (u ^ 0x80000000u) : ~u;
    err = __uint_as_float(fb);  // min distance == |x - e|^2 (expanded form)
  }

  const float4* eq = (const float4*)(emb + (size_t)bidx * DD) + part * 4;
  float4* op = (float4*)(out + (size_t)token * DD) + part * 4;
  float4 v0 = eq[0], v1 = eq[1], v2 = eq[2], v3 = eq[3];
  op[0] = v0; op[1] = v1; op[2] = v2; op[3] = v3;

#pragma unroll
  for (int off = 32; off > 0; off >>= 1) err += __shfl_down(err, off);
  __shared__ float wsum[4];
  const int wid = tid >> 6;
  if ((tid & 63) == 0) wsum[wid] = err;
  __syncthreads();
  if (tid == 0)
    blocksum[blockIdx.x] = (wsum[0] + wsum[1]) + (wsum[2] + wsum[3]);
}

// 1 block: reduce 2048 per-block partials -> loss
__global__ void vq_finish(const float* __restrict__ blocksum,
                          float* __restrict__ out) {
  const int tid = threadIdx.x;
  float s = 0.0f;
#pragma unroll
  for (int i = 0; i < COMBINE_BLOCKS / 256; ++i)
    s += blocksum[i * 256 + tid];
#pragma unroll
  for (int off = 32; off > 0; off >>= 1) s += __shfl_down(s, off);
  __shared__ float wsum[4];
  const int wid = tid >> 6;
  if ((tid & 63) == 0) wsum[wid] = s;
  __syncthreads();
  if (tid == 0) {
    float total = (wsum[0] + wsum[1]) + (wsum[2] + wsum[3]);
    float m = total / (float)QUANT_ELEMS;
    out[LOSS_OFF] = m + 0.25f * m;  // q_latent + COMMITMENT_COST * e_latent
  }
}

extern "C" void kernel_launch(void* const* d_in, const int* in_sizes, int n_in,
                              void* d_out, int out_size, void* d_ws, size_t ws_size,
                              hipStream_t stream) {
  const float* x = (const float*)d_in[0];
  const float* emb = (const float*)d_in[1];
  float* out = (float*)d_out;
  float* ws = (float*)d_ws;
  unsigned long long* packed = (unsigned long long*)(ws + WS_PACKED_F);

  vq_setup<<<580, 256, 0, stream>>>(x, emb, ws);
  vq_dist_mfma<<<NTOK / 128, 256, 0, stream>>>(x, ws, packed);
  vq_combine<<<COMBINE_BLOCKS, 256, 0, stream>>>(emb, packed, out, ws + WS_BSUM);
  vq_finish<<<1, 256, 0, stream>>>(ws + WS_BSUM, out);
}

// Round 10
// 139.377 us; speedup vs baseline: 1.7767x; 1.1014x over previous
//
#include <hip/hip_runtime.h>

// VectorQuantizer: N=131072 tokens, D=64, K=1024 codes.
// out (f32 concat): [0,8388608) quant, [8388608] loss, [8388609,...) idx.
//
// R10: R9 showed dist=61us but total=153.5 — ~92us was auxiliary passes
// (512-block x2 setup re-reading 33.5MB of x, combine's packed round-trip,
// finish, launch gaps). Fuse everything into dist:
//  - x2 computed in-kernel (lanes 0-31/wave, row_sumsq_np8 on L1-hot rows,
//    bit-identical to the old setup pass), broadcast via 512B LDS;
//  - epilogue: quad butterfly leaves ALL 16 lanes holding each token's
//    winning key -> quad gathers winning emb row (L2-hot) and writes quant
//    + idx directly; loss decoded from key, block-reduced to blocksum[1024].
// Pipeline = 3 launches: tiny setup (68 blocks: B-frags + e2), dist, finish.
// Distance math unchanged since R4: fp16 split-product MFMA
// (hi*hi+hi*lo+lo*hi), np8 x2/e2, s=fma(-2,dot,x2+e2), ascending-k
// first-min, bitwise quant copy. R9's proven dbuf/staging/VGPR budget kept.

#define KC 1024
#define DD 64
#define NTOK (32 * 4096)
#define QUANT_ELEMS ((size_t)NTOK * DD)        // 8388608
#define LOSS_OFF QUANT_ELEMS
#define IDX_OFF (QUANT_ELEMS + 1)

// ws float-word offsets
#define WS_E2 0                      // 1024 f32
#define WS_BFRAG_F 2048              // 16384 f16x8 = 65536 f32 words
#define WS_BSUM (WS_BFRAG_F + 65536) // 1024 f32 per-block loss partials

#define DIST_BLOCKS (NTOK / 128)     // 1024

typedef _Float16 f16x8 __attribute__((ext_vector_type(8)));
typedef float f32x4 __attribute__((ext_vector_type(4)));

__device__ __forceinline__ unsigned int sortable_bits(float f) {
  unsigned int b = __float_as_uint(f);
  return b ^ (unsigned int)(((int)b >> 31) | 0x80000000);
}

__device__ __forceinline__ float unsortable_bits(unsigned int u) {
  unsigned int fb = (u & 0x80000000u) ? (u ^ 0x80000000u) : ~u;
  return __uint_as_float(fb);
}

// np pairwise-8 sum of squares of a 64-float row
__device__ __forceinline__ float row_sumsq_np8(const float* p) {
  float r[8];
#pragma unroll
  for (int j = 0; j < 8; ++j) r[j] = p[j] * p[j];
#pragma unroll
  for (int i = 1; i < 8; ++i)
#pragma unroll
    for (int j = 0; j < 8; ++j) {
      float v = p[i * 8 + j];
      r[j] += v * v;
    }
  return ((r[0] + r[1]) + (r[2] + r[3])) + ((r[4] + r[5]) + (r[6] + r[7]));
}

// blocks [0,64): B-frag build; [64,68): e2 table
__global__ void vq_setup(const float* __restrict__ emb,
                         float* __restrict__ ws) {
  const int b = blockIdx.x;
  const int tid = threadIdx.x;
  if (b < 64) {
    const int nt = b;                  // global tile 0..63 (16 codes each)
    const int f = tid >> 6;            // 0..3: plane(hi/lo) x kstep
    const int lane = tid & 63;
    const int plane = f >> 1, ks = f & 1;
    const int n = nt * 16 + (lane & 15);
    const int kb = ks * 32 + ((lane >> 4) & 3) * 8;
    const float* ep = emb + (size_t)n * DD + kb;
    f16x8 o;
#pragma unroll
    for (int j = 0; j < 8; ++j) {
      float v = ep[j];
      _Float16 h = (_Float16)v;
      o[j] = (plane == 0) ? h : (_Float16)(v - (float)h);
    }
    ((f16x8*)(ws + WS_BFRAG_F))[(nt * 4 + f) * 64 + lane] = o;
  } else {
    const int k = (b - 64) * 256 + tid;  // 0..1023
    ws[WS_E2 + k] = row_sumsq_np8(emb + (size_t)k * DD);
  }
}

__launch_bounds__(256, 2)
__global__ void vq_dist_mfma(const float* __restrict__ x_in,
                             const float* __restrict__ emb,
                             const float* __restrict__ ws_ro,
                             float* __restrict__ out,
                             float* __restrict__ blocksum) {
  const int tid = threadIdx.x;
  const int wave = tid >> 6, lane = tid & 63;
  const int quad = lane >> 4, l16 = lane & 15;
  const int tokBase = blockIdx.x * 128 + wave * 32;  // 32 tokens per wave

  __shared__ float4 Bf[2][1024];   // 2 x 16 KB double buffer
  __shared__ float E2s[KC];        // 4 KB
  __shared__ float x2s[128];       // per-block token x2
  __shared__ float wsum[4];

  const float4* bsrc = (const float4*)(ws_ro + WS_BFRAG_F);

  // Preload stage 0 B-frags into registers; stage e2 table to LDS.
  float4 st[4];
#pragma unroll
  for (int i = 0; i < 4; ++i) st[i] = bsrc[i * 256 + tid];
#pragma unroll
  for (int i = 0; i < 4; ++i)
    E2s[i * 256 + tid] = ws_ro[WS_E2 + i * 256 + tid];

  // x2 for this wave's 32 tokens (bit-identical np8, rows L1-hot below)
  if (lane < 32)
    x2s[wave * 32 + lane] =
        row_sumsq_np8(x_in + (size_t)(tokBase + lane) * DD);

  // A fragments: 2 m-sets of 16 tokens; split x into fp16 hi/lo planes.
  f16x8 ah[2][2], al[2][2];
#pragma unroll
  for (int ms = 0; ms < 2; ++ms) {
    const float* xr = x_in + (size_t)(tokBase + ms * 16 + l16) * DD;
#pragma unroll
    for (int ks = 0; ks < 2; ++ks) {
      const float4* p = (const float4*)(xr + ks * 32 + quad * 8);
      float4 v0 = p[0], v1 = p[1];
      float vv[8] = {v0.x, v0.y, v0.z, v0.w, v1.x, v1.y, v1.z, v1.w};
#pragma unroll
      for (int j = 0; j < 8; ++j) {
        _Float16 h = (_Float16)vv[j];
        ah[ms][ks][j] = h;
        al[ms][ks][j] = (_Float16)(vv[j] - (float)h);
      }
    }
  }

#pragma unroll
  for (int i = 0; i < 4; ++i) Bf[0][i * 256 + tid] = st[i];

  float best[2][4];
  int bidx[2][4];
#pragma unroll
  for (int ms = 0; ms < 2; ++ms)
#pragma unroll
    for (int r = 0; r < 4; ++r) { best[ms][r] = 3.402823466e38f; bidx[ms][r] = 0; }

  __syncthreads();  // buf0 + E2s + x2s ready

  // x2 for this lane's C rows: token = tokBase + ms*16 + quad*4 + r
  float x2v[2][4];
#pragma unroll
  for (int ms = 0; ms < 2; ++ms)
#pragma unroll
    for (int r = 0; r < 4; ++r)
      x2v[ms][r] = x2s[wave * 32 + ms * 16 + quad * 4 + r];

  for (int q = 0; q < 16; ++q) {
    const int buf = q & 1;
    // issue next stage's global loads first (overlap with this stage's MFMA)
    if (q < 15) {
#pragma unroll
      for (int i = 0; i < 4; ++i)
        st[i] = bsrc[(q + 1) * 1024 + i * 256 + tid];
    }
    const f16x8* bfp = (const f16x8*)Bf[buf];
#pragma unroll
    for (int lt = 0; lt < 4; ++lt) {
      const int ch = lt * 4;
      f16x8 bh0 = bfp[(ch + 0) * 64 + lane];
      f16x8 bh1 = bfp[(ch + 1) * 64 + lane];
      f16x8 bl0 = bfp[(ch + 2) * 64 + lane];
      f16x8 bl1 = bfp[(ch + 3) * 64 + lane];
      const int ncur = q * 64 + lt * 16 + l16;    // this lane's code column
      const float e2v = E2s[ncur];
      f32x4 acc[2];
#pragma unroll
      for (int ms = 0; ms < 2; ++ms) acc[ms] = (f32x4){0.f, 0.f, 0.f, 0.f};
      // step-major: 2 independent chains; per-acc order identical to R4-R9
#pragma unroll
      for (int ms = 0; ms < 2; ++ms)
        acc[ms] = __builtin_amdgcn_mfma_f32_16x16x32_f16(ah[ms][0], bh0, acc[ms], 0, 0, 0);
#pragma unroll
      for (int ms = 0; ms < 2; ++ms)
        acc[ms] = __builtin_amdgcn_mfma_f32_16x16x32_f16(ah[ms][1], bh1, acc[ms], 0, 0, 0);
#pragma unroll
      for (int ms = 0; ms < 2; ++ms)
        acc[ms] = __builtin_amdgcn_mfma_f32_16x16x32_f16(al[ms][0], bh0, acc[ms], 0, 0, 0);
#pragma unroll
      for (int ms = 0; ms < 2; ++ms)
        acc[ms] = __builtin_amdgcn_mfma_f32_16x16x32_f16(al[ms][1], bh1, acc[ms], 0, 0, 0);
#pragma unroll
      for (int ms = 0; ms < 2; ++ms)
        acc[ms] = __builtin_amdgcn_mfma_f32_16x16x32_f16(ah[ms][0], bl0, acc[ms], 0, 0, 0);
#pragma unroll
      for (int ms = 0; ms < 2; ++ms)
        acc[ms] = __builtin_amdgcn_mfma_f32_16x16x32_f16(ah[ms][1], bl1, acc[ms], 0, 0, 0);
#pragma unroll
      for (int ms = 0; ms < 2; ++ms)
#pragma unroll
        for (int r = 0; r < 4; ++r) {
          float s = __builtin_fmaf(-2.0f, acc[ms][r], x2v[ms][r] + e2v);
          if (s < best[ms][r]) { best[ms][r] = s; bidx[ms][r] = ncur; }
        }
    }
    if (q < 15) {
#pragma unroll
      for (int i = 0; i < 4; ++i) Bf[buf ^ 1][i * 256 + tid] = st[i];
    }
    __syncthreads();
  }

  // Butterfly min across each quad's 16 lanes -> ALL lanes hold the winner.
  unsigned long long key[2][4];
#pragma unroll
  for (int ms = 0; ms < 2; ++ms)
#pragma unroll
    for (int r = 0; r < 4; ++r) {
      unsigned long long k =
          ((unsigned long long)sortable_bits(best[ms][r]) << 32) |
          (unsigned int)bidx[ms][r];
#pragma unroll
      for (int m = 1; m < 16; m <<= 1) {
        unsigned long long o = __shfl_xor(k, m);
        k = o < k ? o : k;
      }
      key[ms][r] = k;
    }

  // Fused epilogue: idx store (quad lane 0), quant gather+store (all lanes),
  // loss partial decoded from keys.
  float qsum = 0.0f;
#pragma unroll
  for (int ms = 0; ms < 2; ++ms)
#pragma unroll
    for (int r = 0; r < 4; ++r) {
      const int token = tokBase + ms * 16 + quad * 4 + r;
      const int widx = (int)(unsigned int)key[ms][r];
      if (l16 == 0) out[IDX_OFF + (size_t)token] = (float)widx;
      // 16 lanes x float4 = the winning 256B row, bitwise copy
      const float4 v = ((const float4*)(emb + (size_t)widx * DD))[l16];
      ((float4*)(out + (size_t)token * DD))[l16] = v;
      qsum += unsortable_bits((unsigned int)(key[ms][r] >> 32));
    }

  // qsum identical across a quad's 16 lanes; sum the 4 quads.
  float tot = __shfl(qsum, 0) + __shfl(qsum, 16) +
              __shfl(qsum, 32) + __shfl(qsum, 48);
  if (lane == 0) wsum[wave] = tot;
  __syncthreads();
  if (tid == 0)
    blocksum[blockIdx.x] = (wsum[0] + wsum[1]) + (wsum[2] + wsum[3]);
}

// 1 block: reduce 1024 per-block partials -> loss
__global__ void vq_finish(const float* __restrict__ blocksum,
                          float* __restrict__ out) {
  const int tid = threadIdx.x;
  float s = 0.0f;
#pragma unroll
  for (int i = 0; i < DIST_BLOCKS / 256; ++i)
    s += blocksum[i * 256 + tid];
#pragma unroll
  for (int off = 32; off > 0; off >>= 1) s += __shfl_down(s, off);
  __shared__ float wsum[4];
  const int wid = tid >> 6;
  if ((tid & 63) == 0) wsum[wid] = s;
  __syncthreads();
  if (tid == 0) {
    float total = (wsum[0] + wsum[1]) + (wsum[2] + wsum[3]);
    float m = total / (float)QUANT_ELEMS;
    out[LOSS_OFF] = m + 0.25f * m;  // q_latent + COMMITMENT_COST * e_latent
  }
}

extern "C" void kernel_launch(void* const* d_in, const int* in_sizes, int n_in,
                              void* d_out, int out_size, void* d_ws, size_t ws_size,
                              hipStream_t stream) {
  const float* x = (const float*)d_in[0];
  const float* emb = (const float*)d_in[1];
  float* out = (float*)d_out;
  float* ws = (float*)d_ws;

  vq_setup<<<68, 256, 0, stream>>>(emb, ws);
  vq_dist_mfma<<<DIST_BLOCKS, 256, 0, stream>>>(x, emb, ws, out, ws + WS_BSUM);
  vq_finish<<<1, 256, 0, stream>>>(ws + WS_BSUM, out);
}